// Round 7
// baseline (3463.754 us; speedup 1.0000x reference)
//
#include <hip/hip_runtime.h>

#define VV 50257
#define DD 50
#define TT 1024
#define BB 1024

__device__ __forceinline__ float rl(float v, int lane) {
    return __int_as_float(__builtin_amdgcn_readlane(__float_as_int(v), lane));
}
__device__ __forceinline__ float sigmf(float x) { return 1.0f / (1.0f + __expf(-x)); }
__device__ __forceinline__ float tanhf_fast(float x) {
    float e = __expf(-2.0f * fabsf(x));
    return copysignf((1.0f - e) / (1.0f + e), x);
}

// P1[v][j] = b1[0][j] + sum_d emb[v][d] * kx1[d][j]   (one-time, ~0.5 GFLOP)
__global__ void proj_emb(const float* __restrict__ emb, const float* __restrict__ kx1,
                         const float* __restrict__ b1, float* __restrict__ P1) {
    int j = threadIdx.x;             // 0..95
    int v0 = blockIdx.x * 8;
    #pragma unroll 1
    for (int vv = 0; vv < 8; ++vv) {
        int v = v0 + vv;
        if (v >= VV) return;
        float acc = b1[j];
        #pragma unroll
        for (int d = 0; d < DD; ++d)
            acc += emb[v * DD + d] * kx1[d * 96 + j];
        P1[v * 96 + j] = acc;
    }
}

// FOUR waves per row, each <= ~110 arch VGPRs (under the allocator's observed
// ~128-150 arch cap, r1/r3/r5/r6 evidence) so NO weights land in AGPRs and the
// ~350/step v_accvgpr_read tax disappears. 1024 blocks x 4 waves = 4 waves/SIMD.
// Roles (per-lane layouts identical to the verified r0/r5 kernels, absmax 0):
//  W0: kh2 rows k=0..31  -> partial m(t-2), written to LDS part0.
//  W1: kh2 rows k=32..63 -> partial m(t-2) in regs; G-phase: combine partials +
//      x(t-2) -> gates -> h2(t-2) (reg + LDS h2s). Owns the GLU tail.
//  W2: GRU1 (kh1 64 wts): h1(t) gates, writes h1s; prefetches P1 rows.
//  W3: kx2 (96 wts): x(t-1) = h1(t-1)·kx2 + b2[0] -> ring xq[(t-1)&1].
// Skews at iter t: W2:h1(t) | W3:x(t-1) | W0/W1:m(t-2) | G: h2(t-2).
// Safety: every LDS write->read pair is separated by exactly one barrier;
// ring parity keeps the next write after the read (xq slot reused every 2
// iters with an intervening full barrier pair). Zero-init h2s/h1s covers the
// pipeline warmup (partials of h2(-1)=0 are naturally zero; combine guarded
// t>=2; W2 guarded t<TT; stale h1/x past the end are never consumed).
__global__ __launch_bounds__(256, 4)
void rnn_main(const int* __restrict__ tokens, const float* __restrict__ P1,
              const float* __restrict__ kh1, const float* __restrict__ b1,
              const float* __restrict__ kx2, const float* __restrict__ kh2,
              const float* __restrict__ b2, const float* __restrict__ wg,
              const float* __restrict__ bg, const float* __restrict__ wd,
              const float* __restrict__ bd, float* __restrict__ out) {
    const int lane = threadIdx.x & 63;
    const int wv   = threadIdx.x >> 6;
    const int row  = blockIdx.x;
    const int l32  = lane & 31;
    const int* __restrict__ trow = tokens + row * TT;

    __shared__ float4 part0[64];      // W0's m-partial {z,r,h}
    __shared__ float4 xq[2][64];      // x-triple ring
    __shared__ float  h1s[64];
    __shared__ float  h2s[64];

    if (threadIdx.x < 64) {
        part0[threadIdx.x] = make_float4(0.f, 0.f, 0.f, 0.f);
        xq[0][threadIdx.x] = make_float4(0.f, 0.f, 0.f, 0.f);
        xq[1][threadIdx.x] = make_float4(0.f, 0.f, 0.f, 0.f);
        h1s[threadIdx.x] = 0.f;
        h2s[threadIdx.x] = 0.f;
    }

    float w[96];
    float f0 = 0.f, f1 = 0.f, f2 = 0.f;
    if (wv == 0) {
        #pragma unroll
        for (int k = 0; k < 32; ++k) {
            w[3 * k]     = kh2[k * 192 + lane];
            w[3 * k + 1] = kh2[k * 192 + 64 + lane];
            w[3 * k + 2] = kh2[k * 192 + 128 + lane];
        }
    } else if (wv == 1) {
        #pragma unroll
        for (int k = 0; k < 32; ++k) {
            w[3 * k]     = kh2[(32 + k) * 192 + lane];
            w[3 * k + 1] = kh2[(32 + k) * 192 + 64 + lane];
            w[3 * k + 2] = kh2[(32 + k) * 192 + 128 + lane];
        }
        f0 = b2[192 + lane]; f1 = b2[256 + lane]; f2 = b2[320 + lane];
    } else if (wv == 2) {
        #pragma unroll
        for (int k = 0; k < 32; ++k) {
            w[k]      = kh1[k * 96 + lane];
            w[32 + k] = (lane < 32) ? kh1[k * 96 + 64 + lane] : 0.f;
        }
        f0 = b1[96 + lane];
        f1 = (lane < 32) ? b1[160 + lane] : 0.f;
    } else {
        #pragma unroll
        for (int k = 0; k < 32; ++k) {
            w[3 * k]     = kx2[k * 192 + lane];
            w[3 * k + 1] = kx2[k * 192 + 64 + lane];
            w[3 * k + 2] = kx2[k * 192 + 128 + lane];
        }
        f0 = b2[lane]; f1 = b2[64 + lane]; f2 = b2[128 + lane];
    }

    float h1 = 0.f;                   // W2 state (lanes>=32 garbage, never read)
    float h2c = 0.f;                  // W1 state; W0 reloads from LDS each iter
    float h1c = 0.f;                  // W3's copy of h1(t-1)
    float mz = 0.f, mr = 0.f, mh = 0.f;  // W1 partial (persists P->G)
    float pz = 0.f, pr = 0.f, ph = 0.f;
    int tok1 = 0;
    if (wv == 2) {
        const float* __restrict__ p = P1 + trow[0] * 96;
        pz = p[l32]; pr = p[32 + l32]; ph = p[64 + l32];
        tok1 = trow[1];
    }

    __syncthreads();

    #pragma unroll 1
    for (int t = 0; t <= TT + 1; ++t) {
        // ---------------- P phase ----------------
        if (wv == 0) {
            float hc = h2s[lane];                 // h2(t-3), written G(t-1)
            float az = 0.f, ar = 0.f, ah = 0.f;
            #pragma unroll
            for (int k = 0; k < 32; ++k) {
                float s = rl(hc, k);
                az += s * w[3 * k];
                ar += s * w[3 * k + 1];
                ah += s * w[3 * k + 2];
            }
            part0[lane] = make_float4(az, ar, ah, 0.f);
        } else if (wv == 1) {
            mz = f0; mr = f1; mh = f2;
            #pragma unroll
            for (int k = 0; k < 32; ++k) {
                float s = rl(h2c, 32 + k);        // own reg = h2(t-3)
                mz += s * w[3 * k];
                mr += s * w[3 * k + 1];
                mh += s * w[3 * k + 2];
            }
        } else if (wv == 2) {
            if (t < TT) {
                int t2 = (t + 2 < TT) ? (t + 2) : (TT - 1);
                const float* __restrict__ pn = P1 + tok1 * 96;
                float pzn = pn[l32], prn = pn[32 + l32], phn = pn[64 + l32];
                int tokn = trow[t2];
                float az = f0, ah = f1;
                #pragma unroll
                for (int k = 0; k < 32; ++k) {
                    float s = rl(h1, k);
                    az += s * w[k];
                    ah += s * w[32 + k];
                }
                float ra  = __shfl_xor(az, 32);   // r-preact to lanes 0..31
                float z1  = sigmf(pz + az);
                float g1  = sigmf(pr + ra);
                float hh1 = tanhf_fast(ph + g1 * ah);
                h1 = z1 * h1 + (1.f - z1) * hh1;  // h1(t)
                h1s[lane] = h1;
                pz = pzn; pr = prn; ph = phn; tok1 = tokn;
            }
        } else {
            // x(t-1) = h1(t-1)·kx2 + b2[0]  -> slot (t-1)&1 (== (t+1)&1)
            float xz = f0, xr = f1, xh = f2;
            #pragma unroll
            for (int k = 0; k < 32; ++k) {
                float s = rl(h1c, k);
                xz += s * w[3 * k];
                xr += s * w[3 * k + 1];
                xh += s * w[3 * k + 2];
            }
            xq[(t + 1) & 1][lane] = make_float4(xz, xr, xh, 0.f);
        }
        __syncthreads();
        // ---------------- G phase ----------------
        if (wv == 1) {
            if (t >= 2) {                         // combine -> h2(t-2)
                float4 pa = part0[lane];
                float4 x  = xq[t & 1][lane];      // x(t-2), written P(t-1)
                float z2  = sigmf(x.x + pa.x + mz);
                float r2  = sigmf(x.y + pa.y + mr);
                float hh2 = tanhf_fast(x.z + r2 * (pa.z + mh));
                h2c = z2 * h2c + (1.f - z2) * hh2;
                h2s[lane] = h2c;
            }
        } else if (wv == 3) {
            h1c = h1s[l32];                       // h1(t), used next iter
        }
        __syncthreads();
    }

    // ---- tail: GLU + dense head on W1 (holds h2(TT-1)) ----
    if (wv == 1) {
        float a0 = bg[lane], a1 = bg[64 + lane], a2 = bg[128 + lane], a3 = bg[192 + lane];
        #pragma unroll
        for (int k = 0; k < 64; ++k) {
            float s = rl(h2c, k);
            a0 += s * wg[k * 256 + lane];
            a1 += s * wg[k * 256 + 64 + lane];
            a2 += s * wg[k * 256 + 128 + lane];
            a3 += s * wg[k * 256 + 192 + lane];
        }
        float g = a0 * sigmf(a2) * wd[lane] + a1 * sigmf(a3) * wd[64 + lane];
        g += __shfl_xor(g, 32); g += __shfl_xor(g, 16); g += __shfl_xor(g, 8);
        g += __shfl_xor(g, 4);  g += __shfl_xor(g, 2);  g += __shfl_xor(g, 1);
        if (lane == 0) out[row] = sigmf(g + bd[0]);
    }
}

extern "C" void kernel_launch(void* const* d_in, const int* in_sizes, int n_in,
                              void* d_out, int out_size, void* d_ws, size_t ws_size,
                              hipStream_t stream) {
    const int*   tokens = (const int*)d_in[0];
    const float* emb = (const float*)d_in[1];
    const float* kx1 = (const float*)d_in[2];
    const float* kh1 = (const float*)d_in[3];
    const float* b1  = (const float*)d_in[4];
    const float* kx2 = (const float*)d_in[5];
    const float* kh2 = (const float*)d_in[6];
    const float* b2  = (const float*)d_in[7];
    const float* wg  = (const float*)d_in[8];
    const float* bg  = (const float*)d_in[9];
    const float* wd  = (const float*)d_in[10];
    const float* bd  = (const float*)d_in[11];
    float* out = (float*)d_out;
    float* P1  = (float*)d_ws;   // needs 50257*96*4 = 19.3 MB of workspace

    proj_emb<<<(VV + 7) / 8, 96, 0, stream>>>(emb, kx1, b1, P1);
    rnn_main<<<BB, 256, 0, stream>>>(tokens, P1, kh1, b1, kx2, kh2, b2,
                                     wg, bg, wd, bd, out);
}

// Round 8
// 1282.597 us; speedup vs baseline: 2.7006x; 2.7006x over previous
//
#include <hip/hip_runtime.h>

#define VV 50257
#define DD 50
#define TT 1024
#define BB 1024

__device__ __forceinline__ float rl(float v, int lane) {
    return __int_as_float(__builtin_amdgcn_readlane(__float_as_int(v), lane));
}
__device__ __forceinline__ float sigmf(float x) { return 1.0f / (1.0f + __expf(-x)); }
__device__ __forceinline__ float tanhf_fast(float x) {
    float e = __expf(-2.0f * fabsf(x));
    return copysignf((1.0f - e) / (1.0f + e), x);
}

// P1[v][j] = b1[0][j] + sum_d emb[v][d] * kx1[d][j]   (one-time, ~0.5 GFLOP)
__global__ void proj_emb(const float* __restrict__ emb, const float* __restrict__ kx1,
                         const float* __restrict__ b1, float* __restrict__ P1) {
    int j = threadIdx.x;             // 0..95
    int v0 = blockIdx.x * 8;
    #pragma unroll 1
    for (int vv = 0; vv < 8; ++vv) {
        int v = v0 + vv;
        if (v >= VV) return;
        float acc = b1[j];
        #pragma unroll
        for (int d = 0; d < DD; ++d)
            acc += emb[v * DD + d] * kx1[d * 96 + j];
        P1[v * 96 + j] = acc;
    }
}

// Two waves per block, ONE row per block, one barrier per step.
// r5 structure (best: 1303 us) with BALANCED barrier phases:
//  Wave B (wv=1) now does GRU1(t+1) AND x(t+1)=h1(t+1)·kx2+b2[0] both
//  PRE-barrier (post-phase empty). Wave A (wv=0) pre: m(t)=h2(t-1)·kh2+b2[1];
//  post: gates -> h2(t).
//  r5's phases were A:520/B:260 pre and A:40/B:270 post -> each wave stalled
//  ~250 cyc/step at the rendezvous (period ~790 issue-cyc). Now A:520+40,
//  B:410+0 -> period ~600. B's 410-cyc phase also hides the P1 (L3) latency.
//  A<->B communicate ONLY via the x-ring now (h1 stays in B, h2 stays in A).
//  Ring safety: slot (t+1)&3 written pre-barrier at iter t, read post-barrier
//  at iter t+1 (>=1 barrier between), rewritten at iter t+4 (>=2 barriers
//  after the read).
//  Per-lane layouts identical to rounds 1/3/4/5 (all passed absmax 0).
__global__ __launch_bounds__(128, 1)
void rnn_main(const int* __restrict__ tokens, const float* __restrict__ P1,
              const float* __restrict__ kh1, const float* __restrict__ b1,
              const float* __restrict__ kx2, const float* __restrict__ kh2,
              const float* __restrict__ b2, const float* __restrict__ wg,
              const float* __restrict__ bg, const float* __restrict__ wd,
              const float* __restrict__ bd, float* __restrict__ out) {
    const int lane = threadIdx.x & 63;
    const int wv   = threadIdx.x >> 6;        // 0 = GRU2 wave, 1 = GRU1+proj wave
    const int row  = blockIdx.x;
    const int l32  = lane & 31;
    const int* __restrict__ trow = tokens + row * TT;

    __shared__ float4 xb[4][64];              // ring of x-triples

    float w[192];
    float f0, f1, f2, f3 = 0.f, f4 = 0.f;     // role-dependent biases

    if (wv == 0) {
        // kh2 columns: z=lane, r=64+lane, h=128+lane, interleaved by k
        #pragma unroll
        for (int k = 0; k < 64; ++k) {
            w[3 * k]     = kh2[k * 192 + lane];
            w[3 * k + 1] = kh2[k * 192 + 64 + lane];
            w[3 * k + 2] = kh2[k * 192 + 128 + lane];
        }
        f0 = b2[192 + lane];                  // recurrent biases b2[1]
        f1 = b2[256 + lane];
        f2 = b2[320 + lane];
    } else {
        // kh1: col lane (z for lane<32, r for lane>=32); h-col 64+lane for lane<32
        // kx2: 3 cols interleaved at w[64..191]
        #pragma unroll
        for (int k = 0; k < 32; ++k) {
            w[k]          = kh1[k * 96 + lane];
            w[32 + k]     = (lane < 32) ? kh1[k * 96 + 64 + lane] : 0.f;
            w[64 + 3 * k] = kx2[k * 192 + lane];
            w[65 + 3 * k] = kx2[k * 192 + 64 + lane];
            w[66 + 3 * k] = kx2[k * 192 + 128 + lane];
        }
        f0 = b1[96 + lane];                   // GRU1 recurrent z/r bias
        f1 = (lane < 32) ? b1[160 + lane] : 0.f;   // GRU1 recurrent h bias
        f2 = b2[lane];                        // input-proj biases b2[0]
        f3 = b2[64 + lane];
        f4 = b2[128 + lane];
    }

    float h1 = 0.f, h2 = 0.f;
    float pz = 0.f, pr = 0.f, ph = 0.f;
    int tokc = 0;
    if (wv == 1) {                            // p-triple for GRU1 step 0
        const float* __restrict__ p = P1 + trow[0] * 96;
        pz = p[l32]; pr = p[32 + l32]; ph = p[64 + l32];
        tokc = trow[1];                       // token for p(t+2) prefetch at t=-1
    }

    float mz, mr, mh;

    #pragma unroll 1
    for (int t = -1; t < TT; ++t) {
        // ---------------- pre-barrier ----------------
        if (wv == 0) {
            if (t >= 0) {
                mz = f0; mr = f1; mh = f2;
                #pragma unroll
                for (int k = 0; k < 64; ++k) {
                    float s = rl(h2, k);
                    mz += s * w[3 * k];
                    mr += s * w[3 * k + 1];
                    mh += s * w[3 * k + 2];
                }
            }
        } else if (t + 1 < TT) {
            // prefetch p(t+2) and token(t+3)
            const float* __restrict__ pn = P1 + tokc * 96;
            float pzn = pn[l32], prn = pn[32 + l32], phn = pn[64 + l32];
            int tokn = trow[(t + 3 < TT) ? (t + 3) : (TT - 1)];
            // GRU1 recurrence: h1(t) -> h1(t+1)
            float az = f0, ah = f1;
            #pragma unroll
            for (int k = 0; k < 32; ++k) {
                float s = rl(h1, k);
                az += s * w[k];
                ah += s * w[32 + k];
            }
            float ra  = __shfl_xor(az, 32);   // r-preact to lanes 0..31
            float z1  = sigmf(pz + az);
            float g1  = sigmf(pr + ra);
            float hh1 = tanhf_fast(ph + g1 * ah);
            h1 = z1 * h1 + (1.f - z1) * hh1;
            // x(t+1) = h1(t+1)·kx2 + b2[0]  -> ring slot (t+1)&3
            float xz = f2, xr = f3, xh = f4;
            #pragma unroll
            for (int k = 0; k < 32; ++k) {
                float s = rl(h1, k);
                xz += s * w[64 + 3 * k];
                xr += s * w[65 + 3 * k];
                xh += s * w[66 + 3 * k];
            }
            xb[(t + 1) & 3][lane] = make_float4(xz, xr, xh, 0.f);
            pz = pzn; pr = prn; ph = phn; tokc = tokn;
        }
        __syncthreads();
        // ---------------- post-barrier ----------------
        if (wv == 0 && t >= 0) {
            float4 x  = xb[t & 3][lane];
            float z2  = sigmf(x.x + mz);
            float r2  = sigmf(x.y + mr);
            float hh2 = tanhf_fast(x.z + r2 * mh);   // reset after recurrent mm
            h2 = z2 * h2 + (1.f - z2) * hh2;
        }
    }

    // ---- tail: GLU + dense head, wave A only (holds h2) ----
    if (wv == 0) {
        float a0 = bg[lane], a1 = bg[64 + lane], a2 = bg[128 + lane], a3 = bg[192 + lane];
        #pragma unroll
        for (int k = 0; k < 64; ++k) {
            float s = rl(h2, k);
            a0 += s * wg[k * 256 + lane];
            a1 += s * wg[k * 256 + 64 + lane];
            a2 += s * wg[k * 256 + 128 + lane];
            a3 += s * wg[k * 256 + 192 + lane];
        }
        float g = a0 * sigmf(a2) * wd[lane] + a1 * sigmf(a3) * wd[64 + lane];
        g += __shfl_xor(g, 32); g += __shfl_xor(g, 16); g += __shfl_xor(g, 8);
        g += __shfl_xor(g, 4);  g += __shfl_xor(g, 2);  g += __shfl_xor(g, 1);
        if (lane == 0) out[row] = sigmf(g + bd[0]);
    }
}

extern "C" void kernel_launch(void* const* d_in, const int* in_sizes, int n_in,
                              void* d_out, int out_size, void* d_ws, size_t ws_size,
                              hipStream_t stream) {
    const int*   tokens = (const int*)d_in[0];
    const float* emb = (const float*)d_in[1];
    const float* kx1 = (const float*)d_in[2];
    const float* kh1 = (const float*)d_in[3];
    const float* b1  = (const float*)d_in[4];
    const float* kx2 = (const float*)d_in[5];
    const float* kh2 = (const float*)d_in[6];
    const float* b2  = (const float*)d_in[7];
    const float* wg  = (const float*)d_in[8];
    const float* bg  = (const float*)d_in[9];
    const float* wd  = (const float*)d_in[10];
    const float* bd  = (const float*)d_in[11];
    float* out = (float*)d_out;
    float* P1  = (float*)d_ws;   // needs 50257*96*4 = 19.3 MB of workspace

    proj_emb<<<(VV + 7) / 8, 96, 0, stream>>>(emb, kx1, b1, P1);
    rnn_main<<<BB, 128, 0, stream>>>(tokens, P1, kh1, b1, kx2, kh2, b2,
                                     wg, bg, wd, bd, out);
}